// Round 1
// baseline (912.698 us; speedup 1.0000x reference)
//
#include <hip/hip_runtime.h>

#define N_NODES 50000
#define N_EDGES 800000
#define F_IN 24
#define HDIM 128
#define N_GRAPHS 100
#define BN_EPS 1e-5f

// ---------------- weight prep: Wcat[k][0:128]=Wtop-Wbot, Wcat[k][128:256]=Wbot ----
__global__ void k_prep_w(const float* __restrict__ W, float* __restrict__ Wcat, int Fhalf) {
    int k = blockIdx.x;           // 0..Fhalf-1
    int j = threadIdx.x;          // 0..255
    float wb = W[(k + Fhalf) * HDIM + (j & 127)];
    float wt = W[k * HDIM + (j & 127)];
    Wcat[k * 256 + j] = (j < HDIM) ? (wt - wb) : wb;
}

// ---------------- edge sort: histogram / scan / scatter --------------------------
__global__ void k_hist(const int* __restrict__ dst, unsigned* __restrict__ deg) {
    int e = blockIdx.x * 256 + threadIdx.x;
    if (e < N_EDGES) atomicAdd(&deg[dst[e]], 1u);
}

__global__ __launch_bounds__(1024) void k_scan(const unsigned* __restrict__ deg,
                                               unsigned* __restrict__ off,
                                               unsigned* __restrict__ cur) {
    __shared__ unsigned s[1024];
    int t = threadIdx.x;
    const int CH = (N_NODES + 1023) / 1024;   // 49
    int lo = t * CH, hi = min(N_NODES, lo + CH);
    unsigned sum = 0;
    for (int i = lo; i < hi; ++i) sum += deg[i];
    s[t] = sum;
    __syncthreads();
    for (int d = 1; d < 1024; d <<= 1) {
        unsigned v = (t >= d) ? s[t - d] : 0u;
        __syncthreads();
        s[t] += v;
        __syncthreads();
    }
    unsigned run = s[t] - sum;   // exclusive base
    for (int i = lo; i < hi; ++i) {
        off[i] = run; cur[i] = run;
        run += deg[i];
    }
}

__global__ void k_scatter(const int* __restrict__ src, const int* __restrict__ dst,
                          unsigned* __restrict__ cur, unsigned* __restrict__ ssrc) {
    int e = blockIdx.x * 256 + threadIdx.x;
    if (e < N_EDGES) {
        unsigned p = atomicAdd(&cur[dst[e]], 1u);
        ssrc[p] = (unsigned)src[e];
    }
}

// ---------------- node matmul: A = bn(X)@(Wt-Wb)+b, C = bn(X)@Wb -----------------
// block: 256 threads, 64 rows x 256 cols; thread tile 8x8
template <int K, bool BN>
__global__ __launch_bounds__(256) void k_mm(const float* __restrict__ X,
                                            const float* __restrict__ Wcat,
                                            const float* __restrict__ bias,
                                            const float* __restrict__ scale,
                                            const float* __restrict__ shift,
                                            float* __restrict__ A, float* __restrict__ C) {
    __shared__ float Tt[64 * K];
    int tid = threadIdx.x;
    int row0 = blockIdx.x * 64;
    for (int i = tid; i < 64 * K; i += 256) {
        int r = i / K, c = i - r * K;
        int row = row0 + r;
        float v = (row < N_NODES) ? X[row * K + c] : 0.f;
        if (BN) v = fmaxf(v * scale[c] + shift[c], 0.f);
        Tt[i] = v;
    }
    __syncthreads();
    int cg = tid & 31, rg = tid >> 5;
    float acc[8][8];
#pragma unroll
    for (int ri = 0; ri < 8; ++ri)
#pragma unroll
        for (int ci = 0; ci < 8; ++ci) {
            int j = cg * 8 + ci;
            acc[ri][ci] = (j < HDIM) ? bias[j] : 0.f;
        }
    for (int k = 0; k < K; ++k) {
        float t[8];
#pragma unroll
        for (int ri = 0; ri < 8; ++ri) t[ri] = Tt[(rg * 8 + ri) * K + k];
        const float4 w0 = *(const float4*)&Wcat[k * 256 + cg * 8];
        const float4 w1 = *(const float4*)&Wcat[k * 256 + cg * 8 + 4];
        float w[8] = {w0.x, w0.y, w0.z, w0.w, w1.x, w1.y, w1.z, w1.w};
#pragma unroll
        for (int ri = 0; ri < 8; ++ri)
#pragma unroll
            for (int ci = 0; ci < 8; ++ci) acc[ri][ci] += t[ri] * w[ci];
    }
    bool isA = (cg < 16);
#pragma unroll
    for (int ri = 0; ri < 8; ++ri) {
        int row = row0 + rg * 8 + ri;
        if (row < N_NODES) {
            float* dstp = isA ? (A + row * HDIM + cg * 8) : (C + row * HDIM + (cg - 16) * 8);
            ((float4*)dstp)[0] = make_float4(acc[ri][0], acc[ri][1], acc[ri][2], acc[ri][3]);
            ((float4*)dstp)[1] = make_float4(acc[ri][4], acc[ri][5], acc[ri][6], acc[ri][7]);
        }
    }
}

// ---------------- aggregation: h[i][k] = deg ? relu(A[i][k] + max_e C[src][k]) : 0
__global__ __launch_bounds__(128) void k_agg(const float* __restrict__ A,
                                             const float* __restrict__ Cc,
                                             const unsigned* __restrict__ off,
                                             const unsigned* __restrict__ deg,
                                             const unsigned* __restrict__ ssrc,
                                             float* __restrict__ H) {
    __shared__ unsigned sl[128];
    int i = blockIdx.x;
    int k = threadIdx.x;
    int d = (int)deg[i];
    unsigned o = off[i];
    float m = -3.4e38f;
    for (int base = 0; base < d; base += 128) {
        int cntc = min(128, d - base);
        __syncthreads();
        if (k < cntc) sl[k] = ssrc[o + base + k];
        __syncthreads();
        for (int e = 0; e < cntc; ++e) {
            unsigned s = sl[e];
            m = fmaxf(m, Cc[s * HDIM + k]);
        }
    }
    float v = (d > 0) ? fmaxf(A[i * HDIM + k] + m, 0.f) : 0.f;
    H[i * HDIM + k] = v;
}

// ---------------- BN stats --------------------------------------------------------
__global__ __launch_bounds__(128) void k_stats(const float* __restrict__ H,
                                               float* __restrict__ sums) {
    int k = threadIdx.x;
    int b = blockIdx.x;          // 250 blocks x 200 rows
    int lo = b * 200, hi = min(N_NODES, lo + 200);
    float s = 0.f, s2 = 0.f;
    for (int r = lo; r < hi; ++r) {
        float v = H[r * HDIM + k];
        s += v; s2 += v * v;
    }
    atomicAdd(&sums[k], s);
    atomicAdd(&sums[HDIM + k], s2);
}

__global__ void k_finstats(const float* __restrict__ sums, const float* __restrict__ g,
                           const float* __restrict__ be, float* __restrict__ scale,
                           float* __restrict__ shift) {
    int k = threadIdx.x;  // 128
    float mean = sums[k] / (float)N_NODES;
    float var = sums[HDIM + k] / (float)N_NODES - mean * mean;
    var = fmaxf(var, 0.f);
    float sc = g[k] / sqrtf(var + BN_EPS);
    scale[k] = sc;
    shift[k] = be[k] - mean * sc;
}

// ---------------- pooling + output -----------------------------------------------
__global__ __launch_bounds__(128) void k_pool(const float* __restrict__ H,
                                              const int* __restrict__ batch,
                                              float* __restrict__ psum,
                                              unsigned* __restrict__ cnt) {
    int b = blockIdx.x;  // 400 blocks x 125 rows
    int k = threadIdx.x;
    int lo = b * 125, hi = lo + 125;
    int curg = batch[lo];
    float acc = 0.f;
    unsigned c = 0;
    for (int r = lo; r < hi; ++r) {
        int gg = batch[r];
        if (gg != curg) {
            atomicAdd(&psum[curg * HDIM + k], acc);
            if (k == 0) atomicAdd(&cnt[curg], c);
            acc = 0.f; c = 0; curg = gg;
        }
        acc += H[r * HDIM + k];
        c++;
    }
    atomicAdd(&psum[curg * HDIM + k], acc);
    if (k == 0) atomicAdd(&cnt[curg], c);
}

__global__ __launch_bounds__(64) void k_out(const float* __restrict__ psum,
                                            const unsigned* __restrict__ cnt,
                                            const float* __restrict__ scale,
                                            const float* __restrict__ shift,
                                            const float* __restrict__ Wl,
                                            const float* __restrict__ bl,
                                            float* __restrict__ out) {
    int g = blockIdx.x;
    int l = threadIdx.x;
    unsigned c = cnt[g];
    float inv = 1.f / fmaxf((float)c, 1.f);
    float acc = 0.f;
    for (int k = l; k < HDIM; k += 64) {
        float pb = (c > 0) ? (scale[k] * (psum[g * HDIM + k] * inv) + shift[k]) : 0.f;
        acc += pb * Wl[k];
    }
    for (int offw = 32; offw > 0; offw >>= 1) acc += __shfl_down(acc, offw);
    if (l == 0) out[g] = fmaxf(acc + bl[0], 0.f);
}

// ---------------- launcher --------------------------------------------------------
extern "C" void kernel_launch(void* const* d_in, const int* in_sizes, int n_in,
                              void* d_out, int out_size, void* d_ws, size_t ws_size,
                              hipStream_t stream) {
    const float* x   = (const float*)d_in[0];
    const int* ei    = (const int*)d_in[1];
    const int* batch = (const int*)d_in[2];
    const float* W1  = (const float*)d_in[3];
    const float* b1  = (const float*)d_in[4];
    const float* W2  = (const float*)d_in[5];
    const float* b2  = (const float*)d_in[6];
    const float* W3  = (const float*)d_in[7];
    const float* b3  = (const float*)d_in[8];
    const float* g1  = (const float*)d_in[9];
    const float* be1 = (const float*)d_in[10];
    const float* g2  = (const float*)d_in[11];
    const float* be2 = (const float*)d_in[12];
    const float* g3  = (const float*)d_in[13];
    const float* be3 = (const float*)d_in[14];
    const float* Wl  = (const float*)d_in[15];
    const float* bl  = (const float*)d_in[16];
    float* out = (float*)d_out;

    const int* srcp = ei;
    const int* dstp = ei + N_EDGES;

    // ---- workspace carve-up (256B aligned) ----
    char* ws = (char*)d_ws;
    size_t o = 0;
    auto alloc = [&](size_t bytes) -> void* {
        o = (o + 255) & ~(size_t)255;
        void* p = ws + o;
        o += bytes;
        return p;
    };
    float* A      = (float*)alloc((size_t)N_NODES * HDIM * 4);
    float* C      = (float*)alloc((size_t)N_NODES * HDIM * 4);
    float* h      = (float*)alloc((size_t)N_NODES * HDIM * 4);
    float* Wcat1  = (float*)alloc((size_t)F_IN * 256 * 4);
    float* Wcat2  = (float*)alloc((size_t)HDIM * 256 * 4);
    float* Wcat3  = (float*)alloc((size_t)HDIM * 256 * 4);
    unsigned* deg  = (unsigned*)alloc((size_t)N_NODES * 4);
    unsigned* off  = (unsigned*)alloc((size_t)N_NODES * 4);
    unsigned* cur  = (unsigned*)alloc((size_t)N_NODES * 4);
    unsigned* ssrc = (unsigned*)alloc((size_t)N_EDGES * 4);
    float* sums    = (float*)alloc(3 * 256 * 4);     // [layer][sum|sumsq]
    float* scbuf   = (float*)alloc(6 * 128 * 4);     // sc1,sh1,sc2,sh2,sc3,sh3
    float* psum    = (float*)alloc((size_t)N_GRAPHS * HDIM * 4);
    unsigned* cnt  = (unsigned*)alloc((size_t)N_GRAPHS * 4);
    (void)ws_size; (void)n_in; (void)in_sizes; (void)out_size;

    float* sums0 = sums;        float* sums1 = sums + 256;  float* sums2 = sums + 512;
    float* sc1 = scbuf;         float* sh1 = scbuf + 128;
    float* sc2 = scbuf + 256;   float* sh2 = scbuf + 384;
    float* sc3 = scbuf + 512;   float* sh3 = scbuf + 640;

    hipMemsetAsync(deg, 0, (size_t)N_NODES * 4, stream);
    hipMemsetAsync(sums, 0, 3 * 256 * 4, stream);
    hipMemsetAsync(psum, 0, (size_t)N_GRAPHS * HDIM * 4, stream);
    hipMemsetAsync(cnt, 0, (size_t)N_GRAPHS * 4, stream);

    // weight prep + edge sort
    k_prep_w<<<F_IN, 256, 0, stream>>>(W1, Wcat1, F_IN);
    k_prep_w<<<HDIM, 256, 0, stream>>>(W2, Wcat2, HDIM);
    k_prep_w<<<HDIM, 256, 0, stream>>>(W3, Wcat3, HDIM);
    k_hist<<<(N_EDGES + 255) / 256, 256, 0, stream>>>(dstp, deg);
    k_scan<<<1, 1024, 0, stream>>>(deg, off, cur);
    k_scatter<<<(N_EDGES + 255) / 256, 256, 0, stream>>>(srcp, dstp, cur, ssrc);

    const int MMG = (N_NODES + 63) / 64;  // 782

    // layer 1
    k_mm<F_IN, false><<<MMG, 256, 0, stream>>>(x, Wcat1, b1, nullptr, nullptr, A, C);
    k_agg<<<N_NODES, 128, 0, stream>>>(A, C, off, deg, ssrc, h);
    k_stats<<<250, 128, 0, stream>>>(h, sums0);
    k_finstats<<<1, 128, 0, stream>>>(sums0, g1, be1, sc1, sh1);

    // layer 2
    k_mm<HDIM, true><<<MMG, 256, 0, stream>>>(h, Wcat2, b2, sc1, sh1, A, C);
    k_agg<<<N_NODES, 128, 0, stream>>>(A, C, off, deg, ssrc, h);
    k_stats<<<250, 128, 0, stream>>>(h, sums1);
    k_finstats<<<1, 128, 0, stream>>>(sums1, g2, be2, sc2, sh2);

    // layer 3
    k_mm<HDIM, true><<<MMG, 256, 0, stream>>>(h, Wcat3, b3, sc2, sh2, A, C);
    k_agg<<<N_NODES, 128, 0, stream>>>(A, C, off, deg, ssrc, h);
    k_stats<<<250, 128, 0, stream>>>(h, sums2);
    k_finstats<<<1, 128, 0, stream>>>(sums2, g3, be3, sc3, sh3);

    // pool + output
    k_pool<<<400, 128, 0, stream>>>(h, batch, psum, cnt);
    k_out<<<N_GRAPHS, 64, 0, stream>>>(psum, cnt, sc3, sh3, Wl, bl, out);
}

// Round 2
// 818.018 us; speedup vs baseline: 1.1157x; 1.1157x over previous
//
#include <hip/hip_runtime.h>

#define N_NODES 50000
#define N_EDGES 800000
#define F_IN 24
#define HDIM 128
#define N_GRAPHS 100
#define BN_EPS 1e-5f
#define NBLK 196  // ceil(N_NODES/256)

// ---------------- weight prep: Wcat[k][0:128]=Wtop-Wbot, Wcat[k][128:256]=Wbot ----
__global__ void k_prep_w(const float* __restrict__ W, float* __restrict__ Wcat, int Fhalf) {
    int k = blockIdx.x;           // 0..Fhalf-1
    int j = threadIdx.x;          // 0..255
    float wb = W[(k + Fhalf) * HDIM + (j & 127)];
    float wt = W[k * HDIM + (j & 127)];
    Wcat[k * 256 + j] = (j < HDIM) ? (wt - wb) : wb;
}

// ---------------- edge sort: histogram / hierarchical scan / scatter -------------
__global__ void k_hist(const int* __restrict__ dst, unsigned* __restrict__ deg) {
    int e = blockIdx.x * 256 + threadIdx.x;
    if (e < N_EDGES) atomicAdd(&deg[dst[e]], 1u);
}

__global__ __launch_bounds__(256) void k_blocksum(const unsigned* __restrict__ deg,
                                                  unsigned* __restrict__ bsum) {
    int i = blockIdx.x * 256 + threadIdx.x;
    unsigned v = (i < N_NODES) ? deg[i] : 0u;
    __shared__ unsigned s[4];
    for (int o = 32; o > 0; o >>= 1) v += __shfl_down(v, o);
    if ((threadIdx.x & 63) == 0) s[threadIdx.x >> 6] = v;
    __syncthreads();
    if (threadIdx.x == 0) bsum[blockIdx.x] = s[0] + s[1] + s[2] + s[3];
}

__global__ __launch_bounds__(256) void k_scanb(const unsigned* __restrict__ bsum,
                                               unsigned* __restrict__ bbase) {
    __shared__ unsigned s[256];
    int t = threadIdx.x;
    unsigned v = (t < NBLK) ? bsum[t] : 0u;
    s[t] = v;
    __syncthreads();
    for (int d = 1; d < 256; d <<= 1) {
        unsigned u = (t >= d) ? s[t - d] : 0u;
        __syncthreads();
        s[t] += u;
        __syncthreads();
    }
    if (t < NBLK) bbase[t] = s[t] - v;  // exclusive
}

__global__ __launch_bounds__(256) void k_offsets(const unsigned* __restrict__ deg,
                                                 const unsigned* __restrict__ bbase,
                                                 unsigned* __restrict__ off,
                                                 unsigned* __restrict__ cur) {
    __shared__ unsigned s[256];
    int t = threadIdx.x;
    int i = blockIdx.x * 256 + t;
    unsigned v = (i < N_NODES) ? deg[i] : 0u;
    s[t] = v;
    __syncthreads();
    for (int d = 1; d < 256; d <<= 1) {
        unsigned u = (t >= d) ? s[t - d] : 0u;
        __syncthreads();
        s[t] += u;
        __syncthreads();
    }
    if (i < N_NODES) {
        unsigned o = bbase[blockIdx.x] + s[t] - v;
        off[i] = o;
        cur[i] = o;
    }
}

__global__ void k_scatter(const int* __restrict__ src, const int* __restrict__ dst,
                          unsigned* __restrict__ cur, unsigned* __restrict__ ssrc) {
    int e = blockIdx.x * 256 + threadIdx.x;
    if (e < N_EDGES) {
        unsigned p = atomicAdd(&cur[dst[e]], 1u);
        ssrc[p] = (unsigned)src[e];
    }
}

// ---------------- node matmul: A = bn(X)@(Wt-Wb)+b, C = bn(X)@Wb -----------------
// block: 256 threads, 64 rows x 256 cols; thread tile 8x8
template <int K, bool BN>
__global__ __launch_bounds__(256) void k_mm(const float* __restrict__ X,
                                            const float* __restrict__ Wcat,
                                            const float* __restrict__ bias,
                                            const float* __restrict__ scale,
                                            const float* __restrict__ shift,
                                            float* __restrict__ A, float* __restrict__ C) {
    __shared__ float Tt[64 * K];
    int tid = threadIdx.x;
    int row0 = blockIdx.x * 64;
    for (int i = tid; i < 64 * K; i += 256) {
        int r = i / K, c = i - r * K;
        int row = row0 + r;
        float v = (row < N_NODES) ? X[row * K + c] : 0.f;
        if (BN) v = fmaxf(v * scale[c] + shift[c], 0.f);
        Tt[i] = v;
    }
    __syncthreads();
    int cg = tid & 31, rg = tid >> 5;
    float acc[8][8];
#pragma unroll
    for (int ri = 0; ri < 8; ++ri)
#pragma unroll
        for (int ci = 0; ci < 8; ++ci) {
            int j = cg * 8 + ci;
            acc[ri][ci] = (j < HDIM) ? bias[j] : 0.f;
        }
    for (int k = 0; k < K; ++k) {
        float t[8];
#pragma unroll
        for (int ri = 0; ri < 8; ++ri) t[ri] = Tt[(rg * 8 + ri) * K + k];
        const float4 w0 = *(const float4*)&Wcat[k * 256 + cg * 8];
        const float4 w1 = *(const float4*)&Wcat[k * 256 + cg * 8 + 4];
        float w[8] = {w0.x, w0.y, w0.z, w0.w, w1.x, w1.y, w1.z, w1.w};
#pragma unroll
        for (int ri = 0; ri < 8; ++ri)
#pragma unroll
            for (int ci = 0; ci < 8; ++ci) acc[ri][ci] += t[ri] * w[ci];
    }
    bool isA = (cg < 16);
#pragma unroll
    for (int ri = 0; ri < 8; ++ri) {
        int row = row0 + rg * 8 + ri;
        if (row < N_NODES) {
            float* dstp = isA ? (A + row * HDIM + cg * 8) : (C + row * HDIM + (cg - 16) * 8);
            ((float4*)dstp)[0] = make_float4(acc[ri][0], acc[ri][1], acc[ri][2], acc[ri][3]);
            ((float4*)dstp)[1] = make_float4(acc[ri][4], acc[ri][5], acc[ri][6], acc[ri][7]);
        }
    }
}

// ---------------- aggregation: h[i][k] = deg ? relu(A[i][k] + max_e C[src][k]) : 0
__global__ __launch_bounds__(128) void k_agg(const float* __restrict__ A,
                                             const float* __restrict__ Cc,
                                             const unsigned* __restrict__ off,
                                             const unsigned* __restrict__ deg,
                                             const unsigned* __restrict__ ssrc,
                                             float* __restrict__ H) {
    __shared__ unsigned sl[128];
    int i = blockIdx.x;
    int k = threadIdx.x;
    int d = (int)deg[i];
    unsigned o = off[i];
    float m = -3.4e38f;
    for (int base = 0; base < d; base += 128) {
        int cntc = min(128, d - base);
        __syncthreads();
        if (k < cntc) sl[k] = ssrc[o + base + k];
        __syncthreads();
        for (int e = 0; e < cntc; ++e) {
            unsigned s = sl[e];
            m = fmaxf(m, Cc[s * HDIM + k]);
        }
    }
    float v = (d > 0) ? fmaxf(A[i * HDIM + k] + m, 0.f) : 0.f;
    H[i * HDIM + k] = v;
}

// ---------------- BN stats --------------------------------------------------------
__global__ __launch_bounds__(128) void k_stats(const float* __restrict__ H,
                                               float* __restrict__ sums) {
    int k = threadIdx.x;
    int b = blockIdx.x;          // 250 blocks x 200 rows
    int lo = b * 200, hi = min(N_NODES, lo + 200);
    float s = 0.f, s2 = 0.f;
    for (int r = lo; r < hi; ++r) {
        float v = H[r * HDIM + k];
        s += v; s2 += v * v;
    }
    atomicAdd(&sums[k], s);
    atomicAdd(&sums[HDIM + k], s2);
}

__global__ void k_finstats(const float* __restrict__ sums, const float* __restrict__ g,
                           const float* __restrict__ be, float* __restrict__ scale,
                           float* __restrict__ shift) {
    int k = threadIdx.x;  // 128
    float mean = sums[k] / (float)N_NODES;
    float var = sums[HDIM + k] / (float)N_NODES - mean * mean;
    var = fmaxf(var, 0.f);
    float sc = g[k] / sqrtf(var + BN_EPS);
    scale[k] = sc;
    shift[k] = be[k] - mean * sc;
}

// ---------------- pooling + output -----------------------------------------------
__global__ __launch_bounds__(128) void k_pool(const float* __restrict__ H,
                                              const int* __restrict__ batch,
                                              float* __restrict__ psum,
                                              unsigned* __restrict__ cnt) {
    int b = blockIdx.x;  // 400 blocks x 125 rows
    int k = threadIdx.x;
    int lo = b * 125, hi = lo + 125;
    int curg = batch[lo];
    float acc = 0.f;
    unsigned c = 0;
    for (int r = lo; r < hi; ++r) {
        int gg = batch[r];
        if (gg != curg) {
            atomicAdd(&psum[curg * HDIM + k], acc);
            if (k == 0) atomicAdd(&cnt[curg], c);
            acc = 0.f; c = 0; curg = gg;
        }
        acc += H[r * HDIM + k];
        c++;
    }
    atomicAdd(&psum[curg * HDIM + k], acc);
    if (k == 0) atomicAdd(&cnt[curg], c);
}

__global__ __launch_bounds__(64) void k_out(const float* __restrict__ psum,
                                            const unsigned* __restrict__ cnt,
                                            const float* __restrict__ scale,
                                            const float* __restrict__ shift,
                                            const float* __restrict__ Wl,
                                            const float* __restrict__ bl,
                                            float* __restrict__ out) {
    int g = blockIdx.x;
    int l = threadIdx.x;
    unsigned c = cnt[g];
    float inv = 1.f / fmaxf((float)c, 1.f);
    float acc = 0.f;
    for (int k = l; k < HDIM; k += 64) {
        float pb = (c > 0) ? (scale[k] * (psum[g * HDIM + k] * inv) + shift[k]) : 0.f;
        acc += pb * Wl[k];
    }
    for (int offw = 32; offw > 0; offw >>= 1) acc += __shfl_down(acc, offw);
    if (l == 0) out[g] = fmaxf(acc + bl[0], 0.f);
}

// ---------------- launcher --------------------------------------------------------
extern "C" void kernel_launch(void* const* d_in, const int* in_sizes, int n_in,
                              void* d_out, int out_size, void* d_ws, size_t ws_size,
                              hipStream_t stream) {
    const float* x   = (const float*)d_in[0];
    const int* ei    = (const int*)d_in[1];
    const int* batch = (const int*)d_in[2];
    const float* W1  = (const float*)d_in[3];
    const float* b1  = (const float*)d_in[4];
    const float* W2  = (const float*)d_in[5];
    const float* b2  = (const float*)d_in[6];
    const float* W3  = (const float*)d_in[7];
    const float* b3  = (const float*)d_in[8];
    const float* g1  = (const float*)d_in[9];
    const float* be1 = (const float*)d_in[10];
    const float* g2  = (const float*)d_in[11];
    const float* be2 = (const float*)d_in[12];
    const float* g3  = (const float*)d_in[13];
    const float* be3 = (const float*)d_in[14];
    const float* Wl  = (const float*)d_in[15];
    const float* bl  = (const float*)d_in[16];
    float* out = (float*)d_out;

    const int* srcp = ei;
    const int* dstp = ei + N_EDGES;

    // ---- workspace carve-up (256B aligned) ----
    char* ws = (char*)d_ws;
    size_t o = 0;
    auto alloc = [&](size_t bytes) -> void* {
        o = (o + 255) & ~(size_t)255;
        void* p = ws + o;
        o += bytes;
        return p;
    };
    float* A      = (float*)alloc((size_t)N_NODES * HDIM * 4);
    float* C      = (float*)alloc((size_t)N_NODES * HDIM * 4);
    float* h      = (float*)alloc((size_t)N_NODES * HDIM * 4);
    float* Wcat1  = (float*)alloc((size_t)F_IN * 256 * 4);
    float* Wcat2  = (float*)alloc((size_t)HDIM * 256 * 4);
    float* Wcat3  = (float*)alloc((size_t)HDIM * 256 * 4);
    unsigned* deg  = (unsigned*)alloc((size_t)N_NODES * 4);
    unsigned* off  = (unsigned*)alloc((size_t)N_NODES * 4);
    unsigned* cur  = (unsigned*)alloc((size_t)N_NODES * 4);
    unsigned* ssrc = (unsigned*)alloc((size_t)N_EDGES * 4);
    unsigned* bsum = (unsigned*)alloc((size_t)NBLK * 4);
    unsigned* bbase= (unsigned*)alloc((size_t)NBLK * 4);
    float* sums    = (float*)alloc(3 * 256 * 4);     // [layer][sum|sumsq]
    float* scbuf   = (float*)alloc(6 * 128 * 4);     // sc1,sh1,sc2,sh2,sc3,sh3
    float* psum    = (float*)alloc((size_t)N_GRAPHS * HDIM * 4);
    unsigned* cnt  = (unsigned*)alloc((size_t)N_GRAPHS * 4);
    (void)ws_size; (void)n_in; (void)in_sizes; (void)out_size;

    float* sums0 = sums;        float* sums1 = sums + 256;  float* sums2 = sums + 512;
    float* sc1 = scbuf;         float* sh1 = scbuf + 128;
    float* sc2 = scbuf + 256;   float* sh2 = scbuf + 384;
    float* sc3 = scbuf + 512;   float* sh3 = scbuf + 640;

    hipMemsetAsync(deg, 0, (size_t)N_NODES * 4, stream);
    hipMemsetAsync(sums, 0, 3 * 256 * 4, stream);
    hipMemsetAsync(psum, 0, (size_t)N_GRAPHS * HDIM * 4, stream);
    hipMemsetAsync(cnt, 0, (size_t)N_GRAPHS * 4, stream);

    // weight prep + edge sort
    k_prep_w<<<F_IN, 256, 0, stream>>>(W1, Wcat1, F_IN);
    k_prep_w<<<HDIM, 256, 0, stream>>>(W2, Wcat2, HDIM);
    k_prep_w<<<HDIM, 256, 0, stream>>>(W3, Wcat3, HDIM);
    k_hist<<<(N_EDGES + 255) / 256, 256, 0, stream>>>(dstp, deg);
    k_blocksum<<<NBLK, 256, 0, stream>>>(deg, bsum);
    k_scanb<<<1, 256, 0, stream>>>(bsum, bbase);
    k_offsets<<<NBLK, 256, 0, stream>>>(deg, bbase, off, cur);
    k_scatter<<<(N_EDGES + 255) / 256, 256, 0, stream>>>(srcp, dstp, cur, ssrc);

    const int MMG = (N_NODES + 63) / 64;  // 782

    // layer 1
    k_mm<F_IN, false><<<MMG, 256, 0, stream>>>(x, Wcat1, b1, nullptr, nullptr, A, C);
    k_agg<<<N_NODES, 128, 0, stream>>>(A, C, off, deg, ssrc, h);
    k_stats<<<250, 128, 0, stream>>>(h, sums0);
    k_finstats<<<1, 128, 0, stream>>>(sums0, g1, be1, sc1, sh1);

    // layer 2
    k_mm<HDIM, true><<<MMG, 256, 0, stream>>>(h, Wcat2, b2, sc1, sh1, A, C);
    k_agg<<<N_NODES, 128, 0, stream>>>(A, C, off, deg, ssrc, h);
    k_stats<<<250, 128, 0, stream>>>(h, sums1);
    k_finstats<<<1, 128, 0, stream>>>(sums1, g2, be2, sc2, sh2);

    // layer 3
    k_mm<HDIM, true><<<MMG, 256, 0, stream>>>(h, Wcat3, b3, sc2, sh2, A, C);
    k_agg<<<N_NODES, 128, 0, stream>>>(A, C, off, deg, ssrc, h);
    k_stats<<<250, 128, 0, stream>>>(h, sums2);
    k_finstats<<<1, 128, 0, stream>>>(sums2, g3, be3, sc3, sh3);

    // pool + output
    k_pool<<<400, 128, 0, stream>>>(h, batch, psum, cnt);
    k_out<<<N_GRAPHS, 64, 0, stream>>>(psum, cnt, sc3, sh3, Wl, bl, out);
}

// Round 3
// 724.187 us; speedup vs baseline: 1.2603x; 1.1296x over previous
//
#include <hip/hip_runtime.h>

#define N_NODES 50000
#define N_EDGES 800000
#define F_IN 24
#define HDIM 128
#define N_GRAPHS 100
#define BN_EPS 1e-5f
#define NBLK 196  // ceil(N_NODES/256)

// ---------------- weight prep: Wcat[k][0:128]=Wtop-Wbot, Wcat[k][128:256]=Wbot ----
__global__ void k_prep_w(const float* __restrict__ W, float* __restrict__ Wcat, int Fhalf) {
    int k = blockIdx.x;           // 0..Fhalf-1
    int j = threadIdx.x;          // 0..255
    float wb = W[(k + Fhalf) * HDIM + (j & 127)];
    float wt = W[k * HDIM + (j & 127)];
    Wcat[k * 256 + j] = (j < HDIM) ? (wt - wb) : wb;
}

// ---------------- edge sort: histogram / hierarchical scan / scatter -------------
__global__ void k_hist(const int* __restrict__ dst, unsigned* __restrict__ deg) {
    int e = blockIdx.x * 256 + threadIdx.x;
    if (e < N_EDGES) atomicAdd(&deg[dst[e]], 1u);
}

__global__ __launch_bounds__(256) void k_blocksum(const unsigned* __restrict__ deg,
                                                  unsigned* __restrict__ bsum) {
    int i = blockIdx.x * 256 + threadIdx.x;
    unsigned v = (i < N_NODES) ? deg[i] : 0u;
    __shared__ unsigned s[4];
    for (int o = 32; o > 0; o >>= 1) v += __shfl_down(v, o);
    if ((threadIdx.x & 63) == 0) s[threadIdx.x >> 6] = v;
    __syncthreads();
    if (threadIdx.x == 0) bsum[blockIdx.x] = s[0] + s[1] + s[2] + s[3];
}

__global__ __launch_bounds__(256) void k_scanb(const unsigned* __restrict__ bsum,
                                               unsigned* __restrict__ bbase) {
    __shared__ unsigned s[256];
    int t = threadIdx.x;
    unsigned v = (t < NBLK) ? bsum[t] : 0u;
    s[t] = v;
    __syncthreads();
    for (int d = 1; d < 256; d <<= 1) {
        unsigned u = (t >= d) ? s[t - d] : 0u;
        __syncthreads();
        s[t] += u;
        __syncthreads();
    }
    if (t < NBLK) bbase[t] = s[t] - v;  // exclusive
}

__global__ __launch_bounds__(256) void k_offsets(const unsigned* __restrict__ deg,
                                                 const unsigned* __restrict__ bbase,
                                                 unsigned* __restrict__ off,
                                                 unsigned* __restrict__ cur) {
    __shared__ unsigned s[256];
    int t = threadIdx.x;
    int i = blockIdx.x * 256 + t;
    unsigned v = (i < N_NODES) ? deg[i] : 0u;
    s[t] = v;
    __syncthreads();
    for (int d = 1; d < 256; d <<= 1) {
        unsigned u = (t >= d) ? s[t - d] : 0u;
        __syncthreads();
        s[t] += u;
        __syncthreads();
    }
    if (i < N_NODES) {
        unsigned o = bbase[blockIdx.x] + s[t] - v;
        off[i] = o;
        cur[i] = o;
    }
}

__global__ void k_scatter(const int* __restrict__ src, const int* __restrict__ dst,
                          unsigned* __restrict__ cur, unsigned* __restrict__ ssrc) {
    int e = blockIdx.x * 256 + threadIdx.x;
    if (e < N_EDGES) {
        unsigned p = atomicAdd(&cur[dst[e]], 1u);
        ssrc[p] = (unsigned)src[e];
    }
}

// ---------------- node matmul: A = bn(X)@(Wt-Wb)+b (y=0), C = bn(X)@Wb (y=1) -----
// block: 256 threads; 64 rows x 128 cols; thread tile 8x4; K-chunked, all LDS.
template <int K, int KC, bool BN>
__global__ __launch_bounds__(256) void k_mm(const float* __restrict__ X,
                                            const float* __restrict__ Wcat,
                                            const float* __restrict__ bias,
                                            const float* __restrict__ scale,
                                            const float* __restrict__ shift,
                                            float* __restrict__ A, float* __restrict__ C) {
    __shared__ float Xs[KC * 68];    // [kk][row], pad 64->68 (16B-aligned rows of 8)
    __shared__ float Ws[KC * 128];   // [kk][col]
    int tid = threadIdx.x;
    int row0 = blockIdx.x * 64;
    const bool isA = (blockIdx.y == 0);
    const int colbase = isA ? 0 : 128;
    int cg = tid & 31;        // col group: cols cg*4..cg*4+3
    int rg = tid >> 5;        // row group: rows rg*8..rg*8+7

    float acc[8][4];
#pragma unroll
    for (int ri = 0; ri < 8; ++ri)
#pragma unroll
        for (int ci = 0; ci < 4; ++ci)
            acc[ri][ci] = isA ? bias[cg * 4 + ci] : 0.f;

    for (int k0 = 0; k0 < K; k0 += KC) {
        __syncthreads();
        // stage X chunk (transposed): Xs[c][r] = bn(X[row0+r][k0+c])
        {
            const int C4 = KC / 4;
            for (int i = tid; i < 64 * C4; i += 256) {
                int c4 = i % C4, r = i / C4;
                int row = row0 + r;
                float4 v = make_float4(0.f, 0.f, 0.f, 0.f);
                if (row < N_NODES) v = *(const float4*)&X[row * K + k0 + c4 * 4];
                if (BN) {
                    int c = k0 + c4 * 4;
                    v.x = fmaxf(v.x * scale[c + 0] + shift[c + 0], 0.f);
                    v.y = fmaxf(v.y * scale[c + 1] + shift[c + 1], 0.f);
                    v.z = fmaxf(v.z * scale[c + 2] + shift[c + 2], 0.f);
                    v.w = fmaxf(v.w * scale[c + 3] + shift[c + 3], 0.f);
                }
                Xs[(c4 * 4 + 0) * 68 + r] = v.x;
                Xs[(c4 * 4 + 1) * 68 + r] = v.y;
                Xs[(c4 * 4 + 2) * 68 + r] = v.z;
                Xs[(c4 * 4 + 3) * 68 + r] = v.w;
            }
        }
        // stage W chunk: Ws[kr][col] = Wcat[k0+kr][colbase+col]
        for (int i = tid; i < KC * 32; i += 256) {
            int c4 = i & 31, kr = i >> 5;
            *(float4*)&Ws[kr * 128 + c4 * 4] =
                *(const float4*)&Wcat[(k0 + kr) * 256 + colbase + c4 * 4];
        }
        __syncthreads();
#pragma unroll
        for (int kk = 0; kk < KC; ++kk) {
            float4 t0 = *(const float4*)&Xs[kk * 68 + rg * 8];
            float4 t1 = *(const float4*)&Xs[kk * 68 + rg * 8 + 4];
            float4 w = *(const float4*)&Ws[kk * 128 + cg * 4];
            float t[8] = {t0.x, t0.y, t0.z, t0.w, t1.x, t1.y, t1.z, t1.w};
            float wv[4] = {w.x, w.y, w.z, w.w};
#pragma unroll
            for (int ri = 0; ri < 8; ++ri)
#pragma unroll
                for (int ci = 0; ci < 4; ++ci)
                    acc[ri][ci] += t[ri] * wv[ci];
        }
    }

    float* __restrict__ dst = isA ? A : C;
#pragma unroll
    for (int ri = 0; ri < 8; ++ri) {
        int row = row0 + rg * 8 + ri;
        if (row < N_NODES)
            *(float4*)&dst[row * HDIM + cg * 4] =
                make_float4(acc[ri][0], acc[ri][1], acc[ri][2], acc[ri][3]);
    }
}

// ---------------- aggregation: h[i][k] = deg ? relu(A[i][k] + max_e C[src][k]) : 0
__global__ __launch_bounds__(128) void k_agg(const float* __restrict__ A,
                                             const float* __restrict__ Cc,
                                             const unsigned* __restrict__ off,
                                             const unsigned* __restrict__ deg,
                                             const unsigned* __restrict__ ssrc,
                                             float* __restrict__ H) {
    __shared__ unsigned sl[128];
    int i = blockIdx.x;
    int k = threadIdx.x;
    int d = (int)deg[i];
    unsigned o = off[i];
    float m = -3.4e38f;
    for (int base = 0; base < d; base += 128) {
        int cntc = min(128, d - base);
        __syncthreads();
        if (k < cntc) sl[k] = ssrc[o + base + k];
        __syncthreads();
        for (int e = 0; e < cntc; ++e) {
            unsigned s = sl[e];
            m = fmaxf(m, Cc[s * HDIM + k]);
        }
    }
    float v = (d > 0) ? fmaxf(A[i * HDIM + k] + m, 0.f) : 0.f;
    H[i * HDIM + k] = v;
}

// ---------------- BN stats --------------------------------------------------------
__global__ __launch_bounds__(128) void k_stats(const float* __restrict__ H,
                                               float* __restrict__ sums) {
    int k = threadIdx.x;
    int b = blockIdx.x;          // 1000 blocks x 50 rows
    int lo = b * 50, hi = min(N_NODES, lo + 50);
    float s = 0.f, s2 = 0.f;
    for (int r = lo; r < hi; ++r) {
        float v = H[r * HDIM + k];
        s += v; s2 += v * v;
    }
    atomicAdd(&sums[k], s);
    atomicAdd(&sums[HDIM + k], s2);
}

__global__ void k_finstats(const float* __restrict__ sums, const float* __restrict__ g,
                           const float* __restrict__ be, float* __restrict__ scale,
                           float* __restrict__ shift) {
    int k = threadIdx.x;  // 128
    float mean = sums[k] / (float)N_NODES;
    float var = sums[HDIM + k] / (float)N_NODES - mean * mean;
    var = fmaxf(var, 0.f);
    float sc = g[k] / sqrtf(var + BN_EPS);
    scale[k] = sc;
    shift[k] = be[k] - mean * sc;
}

// ---------------- pooling + output -----------------------------------------------
__global__ __launch_bounds__(128) void k_pool(const float* __restrict__ H,
                                              const int* __restrict__ batch,
                                              float* __restrict__ psum,
                                              unsigned* __restrict__ cnt) {
    int b = blockIdx.x;  // 400 blocks x 125 rows
    int k = threadIdx.x;
    int lo = b * 125, hi = lo + 125;
    int curg = batch[lo];
    float acc = 0.f;
    unsigned c = 0;
    for (int r = lo; r < hi; ++r) {
        int gg = batch[r];
        if (gg != curg) {
            atomicAdd(&psum[curg * HDIM + k], acc);
            if (k == 0) atomicAdd(&cnt[curg], c);
            acc = 0.f; c = 0; curg = gg;
        }
        acc += H[r * HDIM + k];
        c++;
    }
    atomicAdd(&psum[curg * HDIM + k], acc);
    if (k == 0) atomicAdd(&cnt[curg], c);
}

__global__ __launch_bounds__(64) void k_out(const float* __restrict__ psum,
                                            const unsigned* __restrict__ cnt,
                                            const float* __restrict__ scale,
                                            const float* __restrict__ shift,
                                            const float* __restrict__ Wl,
                                            const float* __restrict__ bl,
                                            float* __restrict__ out) {
    int g = blockIdx.x;
    int l = threadIdx.x;
    unsigned c = cnt[g];
    float inv = 1.f / fmaxf((float)c, 1.f);
    float acc = 0.f;
    for (int k = l; k < HDIM; k += 64) {
        float pb = (c > 0) ? (scale[k] * (psum[g * HDIM + k] * inv) + shift[k]) : 0.f;
        acc += pb * Wl[k];
    }
    for (int offw = 32; offw > 0; offw >>= 1) acc += __shfl_down(acc, offw);
    if (l == 0) out[g] = fmaxf(acc + bl[0], 0.f);
}

// ---------------- launcher --------------------------------------------------------
extern "C" void kernel_launch(void* const* d_in, const int* in_sizes, int n_in,
                              void* d_out, int out_size, void* d_ws, size_t ws_size,
                              hipStream_t stream) {
    const float* x   = (const float*)d_in[0];
    const int* ei    = (const int*)d_in[1];
    const int* batch = (const int*)d_in[2];
    const float* W1  = (const float*)d_in[3];
    const float* b1  = (const float*)d_in[4];
    const float* W2  = (const float*)d_in[5];
    const float* b2  = (const float*)d_in[6];
    const float* W3  = (const float*)d_in[7];
    const float* b3  = (const float*)d_in[8];
    const float* g1  = (const float*)d_in[9];
    const float* be1 = (const float*)d_in[10];
    const float* g2  = (const float*)d_in[11];
    const float* be2 = (const float*)d_in[12];
    const float* g3  = (const float*)d_in[13];
    const float* be3 = (const float*)d_in[14];
    const float* Wl  = (const float*)d_in[15];
    const float* bl  = (const float*)d_in[16];
    float* out = (float*)d_out;

    const int* srcp = ei;
    const int* dstp = ei + N_EDGES;

    // ---- workspace carve-up (256B aligned) ----
    char* ws = (char*)d_ws;
    size_t o = 0;
    auto alloc = [&](size_t bytes) -> void* {
        o = (o + 255) & ~(size_t)255;
        void* p = ws + o;
        o += bytes;
        return p;
    };
    float* A      = (float*)alloc((size_t)N_NODES * HDIM * 4);
    float* C      = (float*)alloc((size_t)N_NODES * HDIM * 4);
    float* h      = (float*)alloc((size_t)N_NODES * HDIM * 4);
    float* Wcat1  = (float*)alloc((size_t)F_IN * 256 * 4);
    float* Wcat2  = (float*)alloc((size_t)HDIM * 256 * 4);
    float* Wcat3  = (float*)alloc((size_t)HDIM * 256 * 4);
    unsigned* deg  = (unsigned*)alloc((size_t)N_NODES * 4);
    unsigned* off  = (unsigned*)alloc((size_t)N_NODES * 4);
    unsigned* cur  = (unsigned*)alloc((size_t)N_NODES * 4);
    unsigned* ssrc = (unsigned*)alloc((size_t)N_EDGES * 4);
    unsigned* bsum = (unsigned*)alloc((size_t)NBLK * 4);
    unsigned* bbase= (unsigned*)alloc((size_t)NBLK * 4);
    float* sums    = (float*)alloc(3 * 256 * 4);     // [layer][sum|sumsq]
    float* scbuf   = (float*)alloc(6 * 128 * 4);     // sc1,sh1,sc2,sh2,sc3,sh3
    float* psum    = (float*)alloc((size_t)N_GRAPHS * HDIM * 4);
    unsigned* cnt  = (unsigned*)alloc((size_t)N_GRAPHS * 4);
    (void)ws_size; (void)n_in; (void)in_sizes; (void)out_size;

    float* sums0 = sums;        float* sums1 = sums + 256;  float* sums2 = sums + 512;
    float* sc1 = scbuf;         float* sh1 = scbuf + 128;
    float* sc2 = scbuf + 256;   float* sh2 = scbuf + 384;
    float* sc3 = scbuf + 512;   float* sh3 = scbuf + 640;

    hipMemsetAsync(deg, 0, (size_t)N_NODES * 4, stream);
    hipMemsetAsync(sums, 0, 3 * 256 * 4, stream);
    hipMemsetAsync(psum, 0, (size_t)N_GRAPHS * HDIM * 4, stream);
    hipMemsetAsync(cnt, 0, (size_t)N_GRAPHS * 4, stream);

    // weight prep + edge sort
    k_prep_w<<<F_IN, 256, 0, stream>>>(W1, Wcat1, F_IN);
    k_prep_w<<<HDIM, 256, 0, stream>>>(W2, Wcat2, HDIM);
    k_prep_w<<<HDIM, 256, 0, stream>>>(W3, Wcat3, HDIM);
    k_hist<<<(N_EDGES + 255) / 256, 256, 0, stream>>>(dstp, deg);
    k_blocksum<<<NBLK, 256, 0, stream>>>(deg, bsum);
    k_scanb<<<1, 256, 0, stream>>>(bsum, bbase);
    k_offsets<<<NBLK, 256, 0, stream>>>(deg, bbase, off, cur);
    k_scatter<<<(N_EDGES + 255) / 256, 256, 0, stream>>>(srcp, dstp, cur, ssrc);

    const dim3 MMG((N_NODES + 63) / 64, 2);  // 782 x 2

    // layer 1
    k_mm<F_IN, F_IN, false><<<MMG, 256, 0, stream>>>(x, Wcat1, b1, nullptr, nullptr, A, C);
    k_agg<<<N_NODES, 128, 0, stream>>>(A, C, off, deg, ssrc, h);
    k_stats<<<1000, 128, 0, stream>>>(h, sums0);
    k_finstats<<<1, 128, 0, stream>>>(sums0, g1, be1, sc1, sh1);

    // layer 2
    k_mm<HDIM, 32, true><<<MMG, 256, 0, stream>>>(h, Wcat2, b2, sc1, sh1, A, C);
    k_agg<<<N_NODES, 128, 0, stream>>>(A, C, off, deg, ssrc, h);
    k_stats<<<1000, 128, 0, stream>>>(h, sums1);
    k_finstats<<<1, 128, 0, stream>>>(sums1, g2, be2, sc2, sh2);

    // layer 3
    k_mm<HDIM, 32, true><<<MMG, 256, 0, stream>>>(h, Wcat3, b3, sc2, sh2, A, C);
    k_agg<<<N_NODES, 128, 0, stream>>>(A, C, off, deg, ssrc, h);
    k_stats<<<1000, 128, 0, stream>>>(h, sums2);
    k_finstats<<<1, 128, 0, stream>>>(sums2, g3, be3, sc3, sh3);

    // pool + output
    k_pool<<<400, 128, 0, stream>>>(h, batch, psum, cnt);
    k_out<<<N_GRAPHS, 64, 0, stream>>>(psum, cnt, sc3, sh3, Wl, bl, out);
}

// Round 4
// 684.106 us; speedup vs baseline: 1.3341x; 1.0586x over previous
//
#include <hip/hip_runtime.h>

#define N_NODES 50000
#define N_EDGES 800000
#define F_IN 24
#define HDIM 128
#define N_GRAPHS 100
#define BN_EPS 1e-5f
#define NBLK 196  // ceil(N_NODES/256)

// ---------------- weight prep: Wcat[k][0:128]=Wtop-Wbot, Wcat[k][128:256]=Wbot ----
__global__ void k_prep_w(const float* __restrict__ W, float* __restrict__ Wcat, int Fhalf) {
    int k = blockIdx.x;           // 0..Fhalf-1
    int j = threadIdx.x;          // 0..255
    float wb = W[(k + Fhalf) * HDIM + (j & 127)];
    float wt = W[k * HDIM + (j & 127)];
    Wcat[k * 256 + j] = (j < HDIM) ? (wt - wb) : wb;
}

// ---------------- edge sort: histogram / hierarchical scan / scatter -------------
__global__ void k_hist(const int* __restrict__ dst, unsigned* __restrict__ deg) {
    int e = blockIdx.x * 256 + threadIdx.x;
    if (e < N_EDGES) atomicAdd(&deg[dst[e]], 1u);
}

__global__ __launch_bounds__(256) void k_blocksum(const unsigned* __restrict__ deg,
                                                  unsigned* __restrict__ bsum) {
    int i = blockIdx.x * 256 + threadIdx.x;
    unsigned v = (i < N_NODES) ? deg[i] : 0u;
    __shared__ unsigned s[4];
    for (int o = 32; o > 0; o >>= 1) v += __shfl_down(v, o);
    if ((threadIdx.x & 63) == 0) s[threadIdx.x >> 6] = v;
    __syncthreads();
    if (threadIdx.x == 0) bsum[blockIdx.x] = s[0] + s[1] + s[2] + s[3];
}

__global__ __launch_bounds__(256) void k_scanb(const unsigned* __restrict__ bsum,
                                               unsigned* __restrict__ bbase) {
    __shared__ unsigned s[256];
    int t = threadIdx.x;
    unsigned v = (t < NBLK) ? bsum[t] : 0u;
    s[t] = v;
    __syncthreads();
    for (int d = 1; d < 256; d <<= 1) {
        unsigned u = (t >= d) ? s[t - d] : 0u;
        __syncthreads();
        s[t] += u;
        __syncthreads();
    }
    if (t < NBLK) bbase[t] = s[t] - v;  // exclusive
}

__global__ __launch_bounds__(256) void k_offsets(const unsigned* __restrict__ deg,
                                                 const unsigned* __restrict__ bbase,
                                                 unsigned* __restrict__ off,
                                                 unsigned* __restrict__ cur) {
    __shared__ unsigned s[256];
    int t = threadIdx.x;
    int i = blockIdx.x * 256 + t;
    unsigned v = (i < N_NODES) ? deg[i] : 0u;
    s[t] = v;
    __syncthreads();
    for (int d = 1; d < 256; d <<= 1) {
        unsigned u = (t >= d) ? s[t - d] : 0u;
        __syncthreads();
        s[t] += u;
        __syncthreads();
    }
    if (i < N_NODES) {
        unsigned o = bbase[blockIdx.x] + s[t] - v;
        off[i] = o;
        cur[i] = o;
    }
}

__global__ void k_scatter(const int* __restrict__ src, const int* __restrict__ dst,
                          unsigned* __restrict__ cur, unsigned* __restrict__ ssrc) {
    int e = blockIdx.x * 256 + threadIdx.x;
    if (e < N_EDGES) {
        unsigned p = atomicAdd(&cur[dst[e]], 1u);
        ssrc[p] = (unsigned)src[e];
    }
}

// ---------------- node matmul: A = bn(X)@(Wt-Wb)+b (y=0), C = bn(X)@Wb (y=1) -----
// block: 256 threads; 64 rows x 128 cols; thread tile 8x4; K-chunked, all LDS.
template <int K, int KC, bool BN>
__global__ __launch_bounds__(256) void k_mm(const float* __restrict__ X,
                                            const float* __restrict__ Wcat,
                                            const float* __restrict__ bias,
                                            const float* __restrict__ scale,
                                            const float* __restrict__ shift,
                                            float* __restrict__ A, float* __restrict__ C) {
    __shared__ float Xs[KC * 68];    // [kk][row], pad 64->68 (16B-aligned rows of 8)
    __shared__ float Ws[KC * 128];   // [kk][col]
    int tid = threadIdx.x;
    int row0 = blockIdx.x * 64;
    const bool isA = (blockIdx.y == 0);
    const int colbase = isA ? 0 : 128;
    int cg = tid & 31;        // col group: cols cg*4..cg*4+3
    int rg = tid >> 5;        // row group: rows rg*8..rg*8+7

    float acc[8][4];
#pragma unroll
    for (int ri = 0; ri < 8; ++ri)
#pragma unroll
        for (int ci = 0; ci < 4; ++ci)
            acc[ri][ci] = isA ? bias[cg * 4 + ci] : 0.f;

    for (int k0 = 0; k0 < K; k0 += KC) {
        __syncthreads();
        // stage X chunk (transposed): Xs[c][r] = bn(X[row0+r][k0+c])
        {
            const int C4 = KC / 4;
            for (int i = tid; i < 64 * C4; i += 256) {
                int c4 = i % C4, r = i / C4;
                int row = row0 + r;
                float4 v = make_float4(0.f, 0.f, 0.f, 0.f);
                if (row < N_NODES) v = *(const float4*)&X[row * K + k0 + c4 * 4];
                if (BN) {
                    int c = k0 + c4 * 4;
                    v.x = fmaxf(v.x * scale[c + 0] + shift[c + 0], 0.f);
                    v.y = fmaxf(v.y * scale[c + 1] + shift[c + 1], 0.f);
                    v.z = fmaxf(v.z * scale[c + 2] + shift[c + 2], 0.f);
                    v.w = fmaxf(v.w * scale[c + 3] + shift[c + 3], 0.f);
                }
                Xs[(c4 * 4 + 0) * 68 + r] = v.x;
                Xs[(c4 * 4 + 1) * 68 + r] = v.y;
                Xs[(c4 * 4 + 2) * 68 + r] = v.z;
                Xs[(c4 * 4 + 3) * 68 + r] = v.w;
            }
        }
        // stage W chunk: Ws[kr][col] = Wcat[k0+kr][colbase+col]
        for (int i = tid; i < KC * 32; i += 256) {
            int c4 = i & 31, kr = i >> 5;
            *(float4*)&Ws[kr * 128 + c4 * 4] =
                *(const float4*)&Wcat[(k0 + kr) * 256 + colbase + c4 * 4];
        }
        __syncthreads();
#pragma unroll
        for (int kk = 0; kk < KC; ++kk) {
            float4 t0 = *(const float4*)&Xs[kk * 68 + rg * 8];
            float4 t1 = *(const float4*)&Xs[kk * 68 + rg * 8 + 4];
            float4 w = *(const float4*)&Ws[kk * 128 + cg * 4];
            float t[8] = {t0.x, t0.y, t0.z, t0.w, t1.x, t1.y, t1.z, t1.w};
            float wv[4] = {w.x, w.y, w.z, w.w};
#pragma unroll
            for (int ri = 0; ri < 8; ++ri)
#pragma unroll
                for (int ci = 0; ci < 4; ++ci)
                    acc[ri][ci] += t[ri] * wv[ci];
        }
    }

    float* __restrict__ dst = isA ? A : C;
#pragma unroll
    for (int ri = 0; ri < 8; ++ri) {
        int row = row0 + rg * 8 + ri;
        if (row < N_NODES)
            *(float4*)&dst[row * HDIM + cg * 4] =
                make_float4(acc[ri][0], acc[ri][1], acc[ri][2], acc[ri][3]);
    }
}

// ---------------- aggregation: h[i][k] = deg ? relu(A[i][k] + max_e C[src][k]) : 0
// edge loop unrolled x8: 8 independent gathers in flight per thread (MLP)
__global__ __launch_bounds__(128) void k_agg(const float* __restrict__ A,
                                             const float* __restrict__ Cc,
                                             const unsigned* __restrict__ off,
                                             const unsigned* __restrict__ deg,
                                             const unsigned* __restrict__ ssrc,
                                             float* __restrict__ H) {
    __shared__ unsigned sl[128];
    int i = blockIdx.x;
    int k = threadIdx.x;
    int d = (int)deg[i];
    unsigned o = off[i];
    float m = -3.4e38f;
    for (int base = 0; base < d; base += 128) {
        int cntc = min(128, d - base);
        __syncthreads();
        if (k < cntc) sl[k] = ssrc[o + base + k];
        __syncthreads();
        int e = 0;
        for (; e + 8 <= cntc; e += 8) {
            unsigned s0 = sl[e + 0], s1 = sl[e + 1], s2 = sl[e + 2], s3 = sl[e + 3];
            unsigned s4 = sl[e + 4], s5 = sl[e + 5], s6 = sl[e + 6], s7 = sl[e + 7];
            float v0 = Cc[s0 * HDIM + k];
            float v1 = Cc[s1 * HDIM + k];
            float v2 = Cc[s2 * HDIM + k];
            float v3 = Cc[s3 * HDIM + k];
            float v4 = Cc[s4 * HDIM + k];
            float v5 = Cc[s5 * HDIM + k];
            float v6 = Cc[s6 * HDIM + k];
            float v7 = Cc[s7 * HDIM + k];
            float m0 = fmaxf(fmaxf(v0, v1), fmaxf(v2, v3));
            float m1 = fmaxf(fmaxf(v4, v5), fmaxf(v6, v7));
            m = fmaxf(m, fmaxf(m0, m1));
        }
        if (e + 4 <= cntc) {
            unsigned s0 = sl[e + 0], s1 = sl[e + 1], s2 = sl[e + 2], s3 = sl[e + 3];
            float v0 = Cc[s0 * HDIM + k];
            float v1 = Cc[s1 * HDIM + k];
            float v2 = Cc[s2 * HDIM + k];
            float v3 = Cc[s3 * HDIM + k];
            m = fmaxf(m, fmaxf(fmaxf(v0, v1), fmaxf(v2, v3)));
            e += 4;
        }
        for (; e < cntc; ++e) {
            unsigned s = sl[e];
            m = fmaxf(m, Cc[s * HDIM + k]);
        }
    }
    float v = (d > 0) ? fmaxf(A[i * HDIM + k] + m, 0.f) : 0.f;
    H[i * HDIM + k] = v;
}

// ---------------- BN stats --------------------------------------------------------
__global__ __launch_bounds__(128) void k_stats(const float* __restrict__ H,
                                               float* __restrict__ sums) {
    int k = threadIdx.x;
    int b = blockIdx.x;          // 1000 blocks x 50 rows
    int lo = b * 50, hi = min(N_NODES, lo + 50);
    float s = 0.f, s2 = 0.f;
    for (int r = lo; r < hi; ++r) {
        float v = H[r * HDIM + k];
        s += v; s2 += v * v;
    }
    atomicAdd(&sums[k], s);
    atomicAdd(&sums[HDIM + k], s2);
}

__global__ void k_finstats(const float* __restrict__ sums, const float* __restrict__ g,
                           const float* __restrict__ be, float* __restrict__ scale,
                           float* __restrict__ shift) {
    int k = threadIdx.x;  // 128
    float mean = sums[k] / (float)N_NODES;
    float var = sums[HDIM + k] / (float)N_NODES - mean * mean;
    var = fmaxf(var, 0.f);
    float sc = g[k] / sqrtf(var + BN_EPS);
    scale[k] = sc;
    shift[k] = be[k] - mean * sc;
}

// ---------------- pooling + output -----------------------------------------------
__global__ __launch_bounds__(128) void k_pool(const float* __restrict__ H,
                                              const int* __restrict__ batch,
                                              float* __restrict__ psum,
                                              unsigned* __restrict__ cnt) {
    int b = blockIdx.x;  // 400 blocks x 125 rows
    int k = threadIdx.x;
    int lo = b * 125, hi = lo + 125;
    int curg = batch[lo];
    float acc = 0.f;
    unsigned c = 0;
    for (int r = lo; r < hi; ++r) {
        int gg = batch[r];
        if (gg != curg) {
            atomicAdd(&psum[curg * HDIM + k], acc);
            if (k == 0) atomicAdd(&cnt[curg], c);
            acc = 0.f; c = 0; curg = gg;
        }
        acc += H[r * HDIM + k];
        c++;
    }
    atomicAdd(&psum[curg * HDIM + k], acc);
    if (k == 0) atomicAdd(&cnt[curg], c);
}

__global__ __launch_bounds__(64) void k_out(const float* __restrict__ psum,
                                            const unsigned* __restrict__ cnt,
                                            const float* __restrict__ scale,
                                            const float* __restrict__ shift,
                                            const float* __restrict__ Wl,
                                            const float* __restrict__ bl,
                                            float* __restrict__ out) {
    int g = blockIdx.x;
    int l = threadIdx.x;
    unsigned c = cnt[g];
    float inv = 1.f / fmaxf((float)c, 1.f);
    float acc = 0.f;
    for (int k = l; k < HDIM; k += 64) {
        float pb = (c > 0) ? (scale[k] * (psum[g * HDIM + k] * inv) + shift[k]) : 0.f;
        acc += pb * Wl[k];
    }
    for (int offw = 32; offw > 0; offw >>= 1) acc += __shfl_down(acc, offw);
    if (l == 0) out[g] = fmaxf(acc + bl[0], 0.f);
}

// ---------------- launcher --------------------------------------------------------
extern "C" void kernel_launch(void* const* d_in, const int* in_sizes, int n_in,
                              void* d_out, int out_size, void* d_ws, size_t ws_size,
                              hipStream_t stream) {
    const float* x   = (const float*)d_in[0];
    const int* ei    = (const int*)d_in[1];
    const int* batch = (const int*)d_in[2];
    const float* W1  = (const float*)d_in[3];
    const float* b1  = (const float*)d_in[4];
    const float* W2  = (const float*)d_in[5];
    const float* b2  = (const float*)d_in[6];
    const float* W3  = (const float*)d_in[7];
    const float* b3  = (const float*)d_in[8];
    const float* g1  = (const float*)d_in[9];
    const float* be1 = (const float*)d_in[10];
    const float* g2  = (const float*)d_in[11];
    const float* be2 = (const float*)d_in[12];
    const float* g3  = (const float*)d_in[13];
    const float* be3 = (const float*)d_in[14];
    const float* Wl  = (const float*)d_in[15];
    const float* bl  = (const float*)d_in[16];
    float* out = (float*)d_out;

    const int* srcp = ei;
    const int* dstp = ei + N_EDGES;

    // ---- workspace carve-up (256B aligned) ----
    char* ws = (char*)d_ws;
    size_t o = 0;
    auto alloc = [&](size_t bytes) -> void* {
        o = (o + 255) & ~(size_t)255;
        void* p = ws + o;
        o += bytes;
        return p;
    };
    float* A      = (float*)alloc((size_t)N_NODES * HDIM * 4);
    float* C      = (float*)alloc((size_t)N_NODES * HDIM * 4);
    float* h      = (float*)alloc((size_t)N_NODES * HDIM * 4);
    float* Wcat1  = (float*)alloc((size_t)F_IN * 256 * 4);
    float* Wcat2  = (float*)alloc((size_t)HDIM * 256 * 4);
    float* Wcat3  = (float*)alloc((size_t)HDIM * 256 * 4);
    unsigned* deg  = (unsigned*)alloc((size_t)N_NODES * 4);
    unsigned* off  = (unsigned*)alloc((size_t)N_NODES * 4);
    unsigned* cur  = (unsigned*)alloc((size_t)N_NODES * 4);
    unsigned* ssrc = (unsigned*)alloc((size_t)N_EDGES * 4);
    unsigned* bsum = (unsigned*)alloc((size_t)NBLK * 4);
    unsigned* bbase= (unsigned*)alloc((size_t)NBLK * 4);
    float* sums    = (float*)alloc(3 * 256 * 4);     // [layer][sum|sumsq]
    float* scbuf   = (float*)alloc(6 * 128 * 4);     // sc1,sh1,sc2,sh2,sc3,sh3
    float* psum    = (float*)alloc((size_t)N_GRAPHS * HDIM * 4);
    unsigned* cnt  = (unsigned*)alloc((size_t)N_GRAPHS * 4);
    (void)ws_size; (void)n_in; (void)in_sizes; (void)out_size;

    float* sums0 = sums;        float* sums1 = sums + 256;  float* sums2 = sums + 512;
    float* sc1 = scbuf;         float* sh1 = scbuf + 128;
    float* sc2 = scbuf + 256;   float* sh2 = scbuf + 384;
    float* sc3 = scbuf + 512;   float* sh3 = scbuf + 640;

    hipMemsetAsync(deg, 0, (size_t)N_NODES * 4, stream);
    hipMemsetAsync(sums, 0, 3 * 256 * 4, stream);
    hipMemsetAsync(psum, 0, (size_t)N_GRAPHS * HDIM * 4, stream);
    hipMemsetAsync(cnt, 0, (size_t)N_GRAPHS * 4, stream);

    // weight prep + edge sort
    k_prep_w<<<F_IN, 256, 0, stream>>>(W1, Wcat1, F_IN);
    k_prep_w<<<HDIM, 256, 0, stream>>>(W2, Wcat2, HDIM);
    k_prep_w<<<HDIM, 256, 0, stream>>>(W3, Wcat3, HDIM);
    k_hist<<<(N_EDGES + 255) / 256, 256, 0, stream>>>(dstp, deg);
    k_blocksum<<<NBLK, 256, 0, stream>>>(deg, bsum);
    k_scanb<<<1, 256, 0, stream>>>(bsum, bbase);
    k_offsets<<<NBLK, 256, 0, stream>>>(deg, bbase, off, cur);
    k_scatter<<<(N_EDGES + 255) / 256, 256, 0, stream>>>(srcp, dstp, cur, ssrc);

    const dim3 MMG((N_NODES + 63) / 64, 2);  // 782 x 2

    // layer 1
    k_mm<F_IN, F_IN, false><<<MMG, 256, 0, stream>>>(x, Wcat1, b1, nullptr, nullptr, A, C);
    k_agg<<<N_NODES, 128, 0, stream>>>(A, C, off, deg, ssrc, h);
    k_stats<<<1000, 128, 0, stream>>>(h, sums0);
    k_finstats<<<1, 128, 0, stream>>>(sums0, g1, be1, sc1, sh1);

    // layer 2
    k_mm<HDIM, 32, true><<<MMG, 256, 0, stream>>>(h, Wcat2, b2, sc1, sh1, A, C);
    k_agg<<<N_NODES, 128, 0, stream>>>(A, C, off, deg, ssrc, h);
    k_stats<<<1000, 128, 0, stream>>>(h, sums1);
    k_finstats<<<1, 128, 0, stream>>>(sums1, g2, be2, sc2, sh2);

    // layer 3
    k_mm<HDIM, 32, true><<<MMG, 256, 0, stream>>>(h, Wcat3, b3, sc2, sh2, A, C);
    k_agg<<<N_NODES, 128, 0, stream>>>(A, C, off, deg, ssrc, h);
    k_stats<<<1000, 128, 0, stream>>>(h, sums2);
    k_finstats<<<1, 128, 0, stream>>>(sums2, g3, be3, sc3, sh3);

    // pool + output
    k_pool<<<400, 128, 0, stream>>>(h, batch, psum, cnt);
    k_out<<<N_GRAPHS, 64, 0, stream>>>(psum, cnt, sc3, sh3, Wl, bl, out);
}

// Round 6
// 605.684 us; speedup vs baseline: 1.5069x; 1.1295x over previous
//
#include <hip/hip_runtime.h>

#define N_NODES 50000
#define N_EDGES 800000
#define F_IN 24
#define HDIM 128
#define N_GRAPHS 100
#define BN_EPS 1e-5f
#define NBLK 196  // ceil(N_NODES/256)

typedef _Float16 h2 __attribute__((ext_vector_type(2)));  // lowers to v_pk_* ops

// ---------------- weight prep: Wcat[k][0:128]=Wtop-Wbot, Wcat[k][128:256]=Wbot ----
__global__ void k_prep_w(const float* __restrict__ W, float* __restrict__ Wcat, int Fhalf) {
    int k = blockIdx.x;           // 0..Fhalf-1
    int j = threadIdx.x;          // 0..255
    float wb = W[(k + Fhalf) * HDIM + (j & 127)];
    float wt = W[k * HDIM + (j & 127)];
    Wcat[k * 256 + j] = (j < HDIM) ? (wt - wb) : wb;
}

// ---------------- edge sort: histogram / hierarchical scan / scatter -------------
__global__ void k_hist(const int* __restrict__ dst, unsigned* __restrict__ deg) {
    int e = blockIdx.x * 256 + threadIdx.x;
    if (e < N_EDGES) atomicAdd(&deg[dst[e]], 1u);
}

__global__ __launch_bounds__(256) void k_blocksum(const unsigned* __restrict__ deg,
                                                  unsigned* __restrict__ bsum) {
    int i = blockIdx.x * 256 + threadIdx.x;
    unsigned v = (i < N_NODES) ? deg[i] : 0u;
    __shared__ unsigned s[4];
    for (int o = 32; o > 0; o >>= 1) v += __shfl_down(v, o);
    if ((threadIdx.x & 63) == 0) s[threadIdx.x >> 6] = v;
    __syncthreads();
    if (threadIdx.x == 0) bsum[blockIdx.x] = s[0] + s[1] + s[2] + s[3];
}

__global__ __launch_bounds__(256) void k_scanb(const unsigned* __restrict__ bsum,
                                               unsigned* __restrict__ bbase) {
    __shared__ unsigned s[256];
    int t = threadIdx.x;
    unsigned v = (t < NBLK) ? bsum[t] : 0u;
    s[t] = v;
    __syncthreads();
    for (int d = 1; d < 256; d <<= 1) {
        unsigned u = (t >= d) ? s[t - d] : 0u;
        __syncthreads();
        s[t] += u;
        __syncthreads();
    }
    if (t < NBLK) bbase[t] = s[t] - v;  // exclusive
}

__global__ __launch_bounds__(256) void k_offsets(const unsigned* __restrict__ deg,
                                                 const unsigned* __restrict__ bbase,
                                                 unsigned* __restrict__ off,
                                                 unsigned* __restrict__ cur) {
    __shared__ unsigned s[256];
    int t = threadIdx.x;
    int i = blockIdx.x * 256 + t;
    unsigned v = (i < N_NODES) ? deg[i] : 0u;
    s[t] = v;
    __syncthreads();
    for (int d = 1; d < 256; d <<= 1) {
        unsigned u = (t >= d) ? s[t - d] : 0u;
        __syncthreads();
        s[t] += u;
        __syncthreads();
    }
    if (i < N_NODES) {
        unsigned o = bbase[blockIdx.x] + s[t] - v;
        off[i] = o;
        cur[i] = o;
    }
}

__global__ void k_scatter(const int* __restrict__ src, const int* __restrict__ dst,
                          unsigned* __restrict__ cur, unsigned* __restrict__ ssrc) {
    int e = blockIdx.x * 256 + threadIdx.x;
    if (e < N_EDGES) {
        unsigned p = atomicAdd(&cur[dst[e]], 1u);
        ssrc[p] = (unsigned)src[e];
    }
}

// ---------------- node matmul: A(fp32) = bn(X)@(Wt-Wb)+b (y=0), C(fp16) = bn(X)@Wb (y=1)
// block: 256 threads; 64 rows x 128 cols; thread tile 8x4; K-chunked, all LDS.
template <int K, int KC, bool BN>
__global__ __launch_bounds__(256) void k_mm(const float* __restrict__ X,
                                            const float* __restrict__ Wcat,
                                            const float* __restrict__ bias,
                                            const float* __restrict__ scale,
                                            const float* __restrict__ shift,
                                            float* __restrict__ A, _Float16* __restrict__ C) {
    __shared__ float Xs[KC * 68];    // [kk][row], pad 64->68 (16B-aligned rows of 8)
    __shared__ float Ws[KC * 128];   // [kk][col]
    int tid = threadIdx.x;
    int row0 = blockIdx.x * 64;
    const bool isA = (blockIdx.y == 0);
    const int colbase = isA ? 0 : 128;
    int cg = tid & 31;        // col group: cols cg*4..cg*4+3
    int rg = tid >> 5;        // row group: rows rg*8..rg*8+7

    float acc[8][4];
#pragma unroll
    for (int ri = 0; ri < 8; ++ri)
#pragma unroll
        for (int ci = 0; ci < 4; ++ci)
            acc[ri][ci] = isA ? bias[cg * 4 + ci] : 0.f;

    for (int k0 = 0; k0 < K; k0 += KC) {
        __syncthreads();
        // stage X chunk (transposed): Xs[c][r] = bn(X[row0+r][k0+c])
        {
            const int C4 = KC / 4;
            for (int i = tid; i < 64 * C4; i += 256) {
                int c4 = i % C4, r = i / C4;
                int row = row0 + r;
                float4 v = make_float4(0.f, 0.f, 0.f, 0.f);
                if (row < N_NODES) v = *(const float4*)&X[row * K + k0 + c4 * 4];
                if (BN) {
                    int c = k0 + c4 * 4;
                    v.x = fmaxf(v.x * scale[c + 0] + shift[c + 0], 0.f);
                    v.y = fmaxf(v.y * scale[c + 1] + shift[c + 1], 0.f);
                    v.z = fmaxf(v.z * scale[c + 2] + shift[c + 2], 0.f);
                    v.w = fmaxf(v.w * scale[c + 3] + shift[c + 3], 0.f);
                }
                Xs[(c4 * 4 + 0) * 68 + r] = v.x;
                Xs[(c4 * 4 + 1) * 68 + r] = v.y;
                Xs[(c4 * 4 + 2) * 68 + r] = v.z;
                Xs[(c4 * 4 + 3) * 68 + r] = v.w;
            }
        }
        // stage W chunk: Ws[kr][col] = Wcat[k0+kr][colbase+col]
        for (int i = tid; i < KC * 32; i += 256) {
            int c4 = i & 31, kr = i >> 5;
            *(float4*)&Ws[kr * 128 + c4 * 4] =
                *(const float4*)&Wcat[(k0 + kr) * 256 + colbase + c4 * 4];
        }
        __syncthreads();
#pragma unroll
        for (int kk = 0; kk < KC; ++kk) {
            float4 t0 = *(const float4*)&Xs[kk * 68 + rg * 8];
            float4 t1 = *(const float4*)&Xs[kk * 68 + rg * 8 + 4];
            float4 w = *(const float4*)&Ws[kk * 128 + cg * 4];
            float t[8] = {t0.x, t0.y, t0.z, t0.w, t1.x, t1.y, t1.z, t1.w};
            float wv[4] = {w.x, w.y, w.z, w.w};
#pragma unroll
            for (int ri = 0; ri < 8; ++ri)
#pragma unroll
                for (int ci = 0; ci < 4; ++ci)
                    acc[ri][ci] += t[ri] * wv[ci];
        }
    }

#pragma unroll
    for (int ri = 0; ri < 8; ++ri) {
        int row = row0 + rg * 8 + ri;
        if (row < N_NODES) {
            if (isA) {
                *(float4*)&A[row * HDIM + cg * 4] =
                    make_float4(acc[ri][0], acc[ri][1], acc[ri][2], acc[ri][3]);
            } else {
                union { h2 h[2]; uint2 u; } pk;
                pk.h[0] = h2{(_Float16)acc[ri][0], (_Float16)acc[ri][1]};
                pk.h[1] = h2{(_Float16)acc[ri][2], (_Float16)acc[ri][3]};
                *(uint2*)&C[row * HDIM + cg * 4] = pk.u;
            }
        }
    }
}

// ---------------- aggregation: h[i][2l..2l+1] = relu(A + max_e C_fp16[src]) ------
// 1 wave per node (64 lanes x 2 ch as packed fp16), 4 nodes/block, 8-deep unroll.
__global__ __launch_bounds__(256) void k_agg(const float* __restrict__ A,
                                             const h2* __restrict__ Cc,   // 64 h2/row
                                             const unsigned* __restrict__ off,
                                             const unsigned* __restrict__ deg,
                                             const unsigned* __restrict__ ssrc,
                                             float* __restrict__ H) {
    __shared__ unsigned sl[4][64];
    int w = threadIdx.x >> 6;       // wave id 0..3
    int lane = threadIdx.x & 63;
    int i = blockIdx.x * 4 + w;     // node (N_NODES divisible by 4)
    int d = (int)deg[i];
    unsigned o = off[i];
    union { unsigned short us[2]; h2 v; } ninf;
    ninf.us[0] = 0xFC00; ninf.us[1] = 0xFC00;  // -inf, -inf
    h2 m2 = ninf.v;
    for (int base = 0; base < d; base += 64) {
        int cntc = min(64, d - base);
        if (lane < cntc) sl[w][lane] = ssrc[o + base + lane];
        // same-wave LDS producer/consumer: compiler inserts lgkmcnt wait, no barrier
        int e = 0;
        for (; e + 8 <= cntc; e += 8) {
            unsigned s0 = sl[w][e + 0], s1 = sl[w][e + 1], s2 = sl[w][e + 2], s3 = sl[w][e + 3];
            unsigned s4 = sl[w][e + 4], s5 = sl[w][e + 5], s6 = sl[w][e + 6], s7 = sl[w][e + 7];
            h2 v0 = Cc[s0 * 64 + lane];
            h2 v1 = Cc[s1 * 64 + lane];
            h2 v2 = Cc[s2 * 64 + lane];
            h2 v3 = Cc[s3 * 64 + lane];
            h2 v4 = Cc[s4 * 64 + lane];
            h2 v5 = Cc[s5 * 64 + lane];
            h2 v6 = Cc[s6 * 64 + lane];
            h2 v7 = Cc[s7 * 64 + lane];
            h2 a0 = __builtin_elementwise_max(v0, v1);
            h2 a1 = __builtin_elementwise_max(v2, v3);
            h2 a2 = __builtin_elementwise_max(v4, v5);
            h2 a3 = __builtin_elementwise_max(v6, v7);
            h2 b0 = __builtin_elementwise_max(a0, a1);
            h2 b1 = __builtin_elementwise_max(a2, a3);
            m2 = __builtin_elementwise_max(m2, __builtin_elementwise_max(b0, b1));
        }
        if (e + 4 <= cntc) {
            unsigned s0 = sl[w][e + 0], s1 = sl[w][e + 1], s2 = sl[w][e + 2], s3 = sl[w][e + 3];
            h2 v0 = Cc[s0 * 64 + lane];
            h2 v1 = Cc[s1 * 64 + lane];
            h2 v2 = Cc[s2 * 64 + lane];
            h2 v3 = Cc[s3 * 64 + lane];
            h2 a0 = __builtin_elementwise_max(v0, v1);
            h2 a1 = __builtin_elementwise_max(v2, v3);
            m2 = __builtin_elementwise_max(m2, __builtin_elementwise_max(a0, a1));
            e += 4;
        }
        for (; e < cntc; ++e)
            m2 = __builtin_elementwise_max(m2, Cc[sl[w][e] * 64 + lane]);
    }
    float2 a = *(const float2*)&A[i * HDIM + lane * 2];
    float2 hv;
    hv.x = (d > 0) ? fmaxf(a.x + (float)m2.x, 0.f) : 0.f;
    hv.y = (d > 0) ? fmaxf(a.y + (float)m2.y, 0.f) : 0.f;
    *(float2*)&H[i * HDIM + lane * 2] = hv;
}

// ---------------- BN stats --------------------------------------------------------
__global__ __launch_bounds__(128) void k_stats(const float* __restrict__ H,
                                               float* __restrict__ sums) {
    int k = threadIdx.x;
    int b = blockIdx.x;          // 1000 blocks x 50 rows
    int lo = b * 50, hi = min(N_NODES, lo + 50);
    float s = 0.f, s2 = 0.f;
    for (int r = lo; r < hi; ++r) {
        float v = H[r * HDIM + k];
        s += v; s2 += v * v;
    }
    atomicAdd(&sums[k], s);
    atomicAdd(&sums[HDIM + k], s2);
}

__global__ void k_finstats(const float* __restrict__ sums, const float* __restrict__ g,
                           const float* __restrict__ be, float* __restrict__ scale,
                           float* __restrict__ shift) {
    int k = threadIdx.x;  // 128
    float mean = sums[k] / (float)N_NODES;
    float var = sums[HDIM + k] / (float)N_NODES - mean * mean;
    var = fmaxf(var, 0.f);
    float sc = g[k] / sqrtf(var + BN_EPS);
    scale[k] = sc;
    shift[k] = be[k] - mean * sc;
}

// ---------------- pooling + output -----------------------------------------------
__global__ __launch_bounds__(128) void k_pool(const float* __restrict__ H,
                                              const int* __restrict__ batch,
                                              float* __restrict__ psum,
                                              unsigned* __restrict__ cnt) {
    int b = blockIdx.x;  // 400 blocks x 125 rows
    int k = threadIdx.x;
    int lo = b * 125, hi = lo + 125;
    int curg = batch[lo];
    float acc = 0.f;
    unsigned c = 0;
    for (int r = lo; r < hi; ++r) {
        int gg = batch[r];
        if (gg != curg) {
            atomicAdd(&psum[curg * HDIM + k], acc);
            if (k == 0) atomicAdd(&cnt[curg], c);
            acc = 0.f; c = 0; curg = gg;
        }
        acc += H[r * HDIM + k];
        c++;
    }
    atomicAdd(&psum[curg * HDIM + k], acc);
    if (k == 0) atomicAdd(&cnt[curg], c);
}

__global__ __launch_bounds__(64) void k_out(const float* __restrict__ psum,
                                            const unsigned* __restrict__ cnt,
                                            const float* __restrict__ scale,
                                            const float* __restrict__ shift,
                                            const float* __restrict__ Wl,
                                            const float* __restrict__ bl,
                                            float* __restrict__ out) {
    int g = blockIdx.x;
    int l = threadIdx.x;
    unsigned c = cnt[g];
    float inv = 1.f / fmaxf((float)c, 1.f);
    float acc = 0.f;
    for (int k = l; k < HDIM; k += 64) {
        float pb = (c > 0) ? (scale[k] * (psum[g * HDIM + k] * inv) + shift[k]) : 0.f;
        acc += pb * Wl[k];
    }
    for (int offw = 32; offw > 0; offw >>= 1) acc += __shfl_down(acc, offw);
    if (l == 0) out[g] = fmaxf(acc + bl[0], 0.f);
}

// ---------------- launcher --------------------------------------------------------
extern "C" void kernel_launch(void* const* d_in, const int* in_sizes, int n_in,
                              void* d_out, int out_size, void* d_ws, size_t ws_size,
                              hipStream_t stream) {
    const float* x   = (const float*)d_in[0];
    const int* ei    = (const int*)d_in[1];
    const int* batch = (const int*)d_in[2];
    const float* W1  = (const float*)d_in[3];
    const float* b1  = (const float*)d_in[4];
    const float* W2  = (const float*)d_in[5];
    const float* b2  = (const float*)d_in[6];
    const float* W3  = (const float*)d_in[7];
    const float* b3  = (const float*)d_in[8];
    const float* g1  = (const float*)d_in[9];
    const float* be1 = (const float*)d_in[10];
    const float* g2  = (const float*)d_in[11];
    const float* be2 = (const float*)d_in[12];
    const float* g3  = (const float*)d_in[13];
    const float* be3 = (const float*)d_in[14];
    const float* Wl  = (const float*)d_in[15];
    const float* bl  = (const float*)d_in[16];
    float* out = (float*)d_out;

    const int* srcp = ei;
    const int* dstp = ei + N_EDGES;

    // ---- workspace carve-up (256B aligned) ----
    char* ws = (char*)d_ws;
    size_t o = 0;
    auto alloc = [&](size_t bytes) -> void* {
        o = (o + 255) & ~(size_t)255;
        void* p = ws + o;
        o += bytes;
        return p;
    };
    float* A      = (float*)alloc((size_t)N_NODES * HDIM * 4);
    _Float16* C   = (_Float16*)alloc((size_t)N_NODES * HDIM * 2);
    float* h      = (float*)alloc((size_t)N_NODES * HDIM * 4);
    float* Wcat1  = (float*)alloc((size_t)F_IN * 256 * 4);
    float* Wcat2  = (float*)alloc((size_t)HDIM * 256 * 4);
    float* Wcat3  = (float*)alloc((size_t)HDIM * 256 * 4);
    unsigned* deg  = (unsigned*)alloc((size_t)N_NODES * 4);
    unsigned* off  = (unsigned*)alloc((size_t)N_NODES * 4);
    unsigned* cur  = (unsigned*)alloc((size_t)N_NODES * 4);
    unsigned* ssrc = (unsigned*)alloc((size_t)N_EDGES * 4);
    unsigned* bsum = (unsigned*)alloc((size_t)NBLK * 4);
    unsigned* bbase= (unsigned*)alloc((size_t)NBLK * 4);
    float* sums    = (float*)alloc(3 * 256 * 4);     // [layer][sum|sumsq]
    float* scbuf   = (float*)alloc(6 * 128 * 4);     // sc1,sh1,sc2,sh2,sc3,sh3
    float* psum    = (float*)alloc((size_t)N_GRAPHS * HDIM * 4);
    unsigned* cnt  = (unsigned*)alloc((size_t)N_GRAPHS * 4);
    (void)ws_size; (void)n_in; (void)in_sizes; (void)out_size;

    float* sums0 = sums;        float* sums1 = sums + 256;  float* sums2 = sums + 512;
    float* sc1 = scbuf;         float* sh1 = scbuf + 128;
    float* sc2 = scbuf + 256;   float* sh2 = scbuf + 384;
    float* sc3 = scbuf + 512;   float* sh3 = scbuf + 640;

    (void)hipMemsetAsync(deg, 0, (size_t)N_NODES * 4, stream);
    (void)hipMemsetAsync(sums, 0, 3 * 256 * 4, stream);
    (void)hipMemsetAsync(psum, 0, (size_t)N_GRAPHS * HDIM * 4, stream);
    (void)hipMemsetAsync(cnt, 0, (size_t)N_GRAPHS * 4, stream);

    // weight prep + edge sort
    k_prep_w<<<F_IN, 256, 0, stream>>>(W1, Wcat1, F_IN);
    k_prep_w<<<HDIM, 256, 0, stream>>>(W2, Wcat2, HDIM);
    k_prep_w<<<HDIM, 256, 0, stream>>>(W3, Wcat3, HDIM);
    k_hist<<<(N_EDGES + 255) / 256, 256, 0, stream>>>(dstp, deg);
    k_blocksum<<<NBLK, 256, 0, stream>>>(deg, bsum);
    k_scanb<<<1, 256, 0, stream>>>(bsum, bbase);
    k_offsets<<<NBLK, 256, 0, stream>>>(deg, bbase, off, cur);
    k_scatter<<<(N_EDGES + 255) / 256, 256, 0, stream>>>(srcp, dstp, cur, ssrc);

    const dim3 MMG((N_NODES + 63) / 64, 2);  // 782 x 2
    const int AGB = N_NODES / 4;             // 12500 blocks, 4 nodes each

    // layer 1
    k_mm<F_IN, F_IN, false><<<MMG, 256, 0, stream>>>(x, Wcat1, b1, nullptr, nullptr, A, C);
    k_agg<<<AGB, 256, 0, stream>>>(A, (const h2*)C, off, deg, ssrc, h);
    k_stats<<<1000, 128, 0, stream>>>(h, sums0);
    k_finstats<<<1, 128, 0, stream>>>(sums0, g1, be1, sc1, sh1);

    // layer 2
    k_mm<HDIM, 32, true><<<MMG, 256, 0, stream>>>(h, Wcat2, b2, sc1, sh1, A, C);
    k_agg<<<AGB, 256, 0, stream>>>(A, (const h2*)C, off, deg, ssrc, h);
    k_stats<<<1000, 128, 0, stream>>>(h, sums1);
    k_finstats<<<1, 128, 0, stream>>>(sums1, g2, be2, sc2, sh2);

    // layer 3
    k_mm<HDIM, 32, true><<<MMG, 256, 0, stream>>>(h, Wcat3, b3, sc2, sh2, A, C);
    k_agg<<<AGB, 256, 0, stream>>>(A, (const h2*)C, off, deg, ssrc, h);
    k_stats<<<1000, 128, 0, stream>>>(h, sums2);
    k_finstats<<<1, 128, 0, stream>>>(sums2, g3, be3, sc3, sh3);

    // pool + output
    k_pool<<<400, 128, 0, stream>>>(h, batch, psum, cnt);
    k_out<<<N_GRAPHS, 64, 0, stream>>>(psum, cnt, sc3, sh3, Wl, bl, out);
}